// Round 3
// baseline (461.608 us; speedup 1.0000x reference)
//
#include <hip/hip_runtime.h>
#include <math.h>

// Problem constants (from reference)
#define NN 50000
#define NE 800000
#define NFEAT 128
#define NHID 64
#define NCLASS 16
#define NB_SCAN ((NN + 255) / 256)  // 196
#define GB ((NN + 63) / 64)         // 782 row-tiles for layer-1 GEMM
#define SC_CHUNKS 128               // scatter chunks per row-group
#define ROWS_G8 ((NN + 7) / 8)      // 6250 rows per scatter group

// fp32 <-> bf16 helpers (RNE round)
__device__ inline unsigned short f2bf(float f) {
    unsigned u = __builtin_bit_cast(unsigned, f);
    u += 0x7fffu + ((u >> 16) & 1u);
    return (unsigned short)(u >> 16);
}
__device__ inline float bf2f(unsigned short h) {
    return __builtin_bit_cast(float, (unsigned)h << 16);
}
// Packed edge: low 16 = col (NN < 65536), high 16 = weight as bf16.
__device__ inline float pk_w(unsigned v) { return bf2f((unsigned short)(v >> 16)); }
__device__ inline int pk_c(unsigned v) { return (int)(v & 0xffffu); }

// ---------------- CSR build ----------------

// Pack + rank: atomicAdd's return value IS the edge's rank within its row.
// rr8.x = row<<16 | rank ; rr8.y = wbf16<<16 | col  (== final pk word).
__global__ __launch_bounds__(256) void hist_pack_kernel(const int* __restrict__ erow,
                                                        const int* __restrict__ ecol,
                                                        const float* __restrict__ ew,
                                                        int* __restrict__ deg,
                                                        uint2* __restrict__ rr8, int E) {
    int e = blockIdx.x * 256 + threadIdx.x;
    if (e < E) {
        int r = erow[e];
        int k = atomicAdd(&deg[r], 1);
        uint2 v;
        v.x = ((unsigned)r << 16) | (unsigned)k;
        v.y = ((unsigned)f2bf(ew[e]) << 16) | (unsigned)ecol[e];
        rr8[e] = v;
    }
}

__global__ __launch_bounds__(256) void scan_sum_kernel(const int* __restrict__ deg,
                                                       int* __restrict__ blocksum, int n) {
    __shared__ int s[256];
    const int t = threadIdx.x;
    int i = blockIdx.x * 256 + t;
    s[t] = (i < n) ? deg[i] : 0;
    __syncthreads();
#pragma unroll
    for (int off = 128; off > 0; off >>= 1) {
        if (t < off) s[t] += s[t + off];
        __syncthreads();
    }
    if (t == 0) blocksum[blockIdx.x] = s[0];
}

// Merged top-level + final scan: each block scans the 196 block-sums in LDS itself.
__global__ __launch_bounds__(256) void scan_final_kernel(const int* __restrict__ deg,
                                                         const int* __restrict__ blocksum,
                                                         int* __restrict__ row_ptr, int n) {
    __shared__ int bs[256];
    __shared__ int s[256];
    const int t = threadIdx.x;
    bs[t] = (t < NB_SCAN) ? blocksum[t] : 0;
    __syncthreads();
    for (int off = 1; off < 256; off <<= 1) {
        int u = (t >= off) ? bs[t - off] : 0;
        __syncthreads();
        bs[t] += u;
        __syncthreads();
    }
    const int blockpre = (blockIdx.x == 0) ? 0 : bs[blockIdx.x - 1];

    int i = blockIdx.x * 256 + t;
    int d = (i < n) ? deg[i] : 0;
    s[t] = d;
    __syncthreads();
    for (int off = 1; off < 256; off <<= 1) {
        int u = (t >= off) ? s[t - off] : 0;
        __syncthreads();
        s[t] += u;
        __syncthreads();
    }
    int excl = blockpre + s[t] - d;
    if (i < n) {
        row_ptr[i] = excl;
        if (i == n - 1) row_ptr[n] = excl + d;
    }
}

// XCD-affine scatter: 8 row-groups, each ~0.4MB of pk written ONLY from the XCD
// that owns it (true XCC_ID from hardware + per-group chunk queue), so L2
// write-combines full 64B lines -> HBM writes ~= pk size, not 16x amplified.
// Fallback sweep over other groups guarantees coverage under any dispatch map.
__global__ __launch_bounds__(256) void scatter8_kernel(const uint2* __restrict__ rr8,
                                                       const int* __restrict__ row_ptr,
                                                       int* __restrict__ qcur,
                                                       unsigned* __restrict__ pk, int E) {
    __shared__ int s_chunk;
    const int t = threadIdx.x;
    int myg;
    asm volatile("s_getreg_b32 %0, hwreg(HW_REG_XCC_ID, 0, 32)" : "=s"(myg));
    myg &= 7;
    const int CH = (E + SC_CHUNKS - 1) / SC_CHUNKS;
    for (int gg = 0; gg < 8; gg++) {
        const int g = (myg + gg) & 7;
        const int rlo = g * ROWS_G8;
        const int rhi = (rlo + ROWS_G8 < NN) ? rlo + ROWS_G8 : NN;
        for (;;) {
            if (t == 0) s_chunk = atomicAdd(&qcur[g], 1);
            __syncthreads();
            const int chunk = s_chunk;
            __syncthreads();
            if (chunk >= SC_CHUNKS) break;
            const int lo = chunk * CH;
            const int hi = (lo + CH < E) ? lo + CH : E;
            for (int e = lo + t; e < hi; e += 256) {
                uint2 v = rr8[e];
                int r = (int)(v.x >> 16);
                if (r >= rlo && r < rhi) {
                    pk[row_ptr[r] + (int)(v.x & 0xffffu)] = v.y;
                }
            }
        }
    }
}

// ---------------- Layer-1 GEMM: out[M,64] = in[M,128] @ W[128,64], bf16 out ----------------
template <int K, bool RELU_IN>
__global__ __launch_bounds__(256) void gemm64_kernel(const float* __restrict__ in,
                                                     const float* __restrict__ Wg,
                                                     unsigned short* __restrict__ outb, int M) {
    constexpr int KC = 64;
    __shared__ float xs[KC][68];
    __shared__ float Ws[KC][64];
    const int t = threadIdx.x;
    const int tx = t % 16;
    const int ty = t / 16;
    const int r0 = blockIdx.x * 64;

    float acc[4][4];
#pragma unroll
    for (int i = 0; i < 4; i++)
#pragma unroll
        for (int j = 0; j < 4; j++) acc[i][j] = 0.f;

    for (int k0 = 0; k0 < K; k0 += KC) {
        for (int i = t * 4; i < KC * 64; i += 1024) {
            *(float4*)&Ws[i / 64][i % 64] = *(const float4*)&Wg[(size_t)k0 * 64 + i];
        }
        {
            const int r = t / 4;
            const int q = t % 4;
            const int gr = r0 + r;
#pragma unroll
            for (int i = 0; i < 4; i++) {
                int k = q * 16 + i * 4;
                float4 v;
                if (gr < M)
                    v = *(const float4*)&in[(size_t)gr * K + k0 + k];
                else
                    v = make_float4(0.f, 0.f, 0.f, 0.f);
                if (RELU_IN) {
                    v.x = fmaxf(v.x, 0.f);
                    v.y = fmaxf(v.y, 0.f);
                    v.z = fmaxf(v.z, 0.f);
                    v.w = fmaxf(v.w, 0.f);
                }
                xs[k + 0][r] = v.x;
                xs[k + 1][r] = v.y;
                xs[k + 2][r] = v.z;
                xs[k + 3][r] = v.w;
            }
        }
        __syncthreads();
#pragma unroll 8
        for (int k = 0; k < KC; k++) {
            float4 xv = *(const float4*)&xs[k][ty * 4];
            float4 wv = *(const float4*)&Ws[k][tx * 4];
            acc[0][0] += xv.x * wv.x; acc[0][1] += xv.x * wv.y;
            acc[0][2] += xv.x * wv.z; acc[0][3] += xv.x * wv.w;
            acc[1][0] += xv.y * wv.x; acc[1][1] += xv.y * wv.y;
            acc[1][2] += xv.y * wv.z; acc[1][3] += xv.y * wv.w;
            acc[2][0] += xv.z * wv.x; acc[2][1] += xv.z * wv.y;
            acc[2][2] += xv.z * wv.z; acc[2][3] += xv.z * wv.w;
            acc[3][0] += xv.w * wv.x; acc[3][1] += xv.w * wv.y;
            acc[3][2] += xv.w * wv.z; acc[3][3] += xv.w * wv.w;
        }
        __syncthreads();
    }
#pragma unroll
    for (int i = 0; i < 4; i++) {
        int r = r0 + ty * 4 + i;
        if (r < M) {
            ushort4 u;
            u.x = f2bf(acc[i][0]);
            u.y = f2bf(acc[i][1]);
            u.z = f2bf(acc[i][2]);
            u.w = f2bf(acc[i][3]);
            *(ushort4*)&outb[(size_t)r * 64 + tx * 4] = u;
        }
    }
}

// ---------------- Fused SpMM(F=64) + next-layer dense GEMM ----------------
// One row per wave64 (F=64 == wave width): edge words are wave-uniform,
// gathers are 1 ushort per lane = one 128B line per edge, zero divergence.
// Epilogue: block's 8 rows -> LDS, relu, 8x64 @ W(64xNOUT) -> bf16 nxt buffer.
template <int NOUT>
__global__ __launch_bounds__(512) void spmm64_fused_kernel(
    const unsigned short* __restrict__ gb,   // gather source [*,64] bf16
    const int* __restrict__ row_ptr,
    const unsigned* __restrict__ pk,
    const float* __restrict__ bias,
    const float* __restrict__ Wn,            // [64, NOUT] fp32 (next layer)
    float* __restrict__ e_out,               // [M,64] fp32 (required output)
    unsigned short* __restrict__ nxt,        // [M,NOUT] bf16 (next layer input)
    int M) {
    __shared__ float Wlt[NOUT][65];          // transposed: Wlt[j][k]
    __shared__ float xs[8][64];
    const int t = threadIdx.x;

    for (int idx = t; idx < 64 * NOUT; idx += 512) {
        int k = idx / NOUT, j = idx % NOUT;
        Wlt[j][k] = Wn[idx];
    }

    const int wv = __builtin_amdgcn_readfirstlane(t >> 6);  // wave id 0..7 (uniform)
    const int lane = t & 63;
    int r = blockIdx.x * 8 + wv;
    if (r >= M) r = M - 1;  // defensive; grid sized exactly (50000/8)

    float a = 0.f;
    int e = row_ptr[r];
    const int end = row_ptr[r + 1];
    for (; e + 8 <= end; e += 8) {
        unsigned q0 = pk[e + 0], q1 = pk[e + 1], q2 = pk[e + 2], q3 = pk[e + 3];
        unsigned q4 = pk[e + 4], q5 = pk[e + 5], q6 = pk[e + 6], q7 = pk[e + 7];
        a += pk_w(q0) * bf2f(gb[(size_t)pk_c(q0) * 64 + lane]);
        a += pk_w(q1) * bf2f(gb[(size_t)pk_c(q1) * 64 + lane]);
        a += pk_w(q2) * bf2f(gb[(size_t)pk_c(q2) * 64 + lane]);
        a += pk_w(q3) * bf2f(gb[(size_t)pk_c(q3) * 64 + lane]);
        a += pk_w(q4) * bf2f(gb[(size_t)pk_c(q4) * 64 + lane]);
        a += pk_w(q5) * bf2f(gb[(size_t)pk_c(q5) * 64 + lane]);
        a += pk_w(q6) * bf2f(gb[(size_t)pk_c(q6) * 64 + lane]);
        a += pk_w(q7) * bf2f(gb[(size_t)pk_c(q7) * 64 + lane]);
    }
    for (; e < end; ++e) {
        unsigned q = pk[e];
        a += pk_w(q) * bf2f(gb[(size_t)pk_c(q) * 64 + lane]);
    }
    float v = a + bias[lane];
    e_out[(size_t)r * 64 + lane] = v;
    xs[wv][lane] = fmaxf(v, 0.f);
    __syncthreads();

    // Epilogue GEMM: nxt[r][j] = sum_k relu(e[r][k]) * W[k][j]
    if (NOUT == 64) {
        const int rr = t >> 6;   // wave-uniform -> xs reads broadcast (free)
        const int j = t & 63;
        float acc = 0.f;
#pragma unroll 16
        for (int k = 0; k < 64; k++) acc += xs[rr][k] * Wlt[j][k];
        int gr = blockIdx.x * 8 + rr;
        if (gr < M) nxt[(size_t)gr * 64 + j] = f2bf(acc);
    } else {
        if (t < 8 * NOUT) {
            const int rr = t / NOUT;
            const int j = t % NOUT;
            float acc = 0.f;
#pragma unroll 16
            for (int k = 0; k < 64; k++) acc += xs[rr][k] * Wlt[j][k];
            int gr = blockIdx.x * 8 + rr;
            if (gr < M) nxt[(size_t)gr * NOUT + j] = f2bf(acc);
        }
    }
}

// ---------------- SpMM (F=16) fused with log_softmax ----------------
// One row per wave64: lane = 16*slot + f, 4 edge slots in parallel, shfl-reduce.
__global__ __launch_bounds__(256) void spmm16_lsm_kernel(const unsigned short* __restrict__ tmpc,
                                                         const int* __restrict__ row_ptr,
                                                         const unsigned* __restrict__ pk,
                                                         const float* __restrict__ bias,
                                                         float* __restrict__ e5,
                                                         float* __restrict__ out0, int M) {
    const int t = threadIdx.x;
    const int wv = __builtin_amdgcn_readfirstlane(t >> 6);  // wave 0..3
    const int lane = t & 63;
    const int f = lane & 15;
    const int s = lane >> 4;  // slot 0..3
    const int r = blockIdx.x * 4 + wv;
    if (r >= M) return;

    int e = row_ptr[r];
    const int end = row_ptr[r + 1];
    float acc = 0.f;
    for (; e + 8 <= end; e += 8) {
        unsigned qa = pk[e + s];
        unsigned qb = pk[e + 4 + s];
        acc += pk_w(qa) * bf2f(tmpc[(size_t)pk_c(qa) * 16 + f]);
        acc += pk_w(qb) * bf2f(tmpc[(size_t)pk_c(qb) * 16 + f]);
    }
    if (e + 4 <= end) {
        unsigned q = pk[e + s];
        acc += pk_w(q) * bf2f(tmpc[(size_t)pk_c(q) * 16 + f]);
        e += 4;
    }
    if (s < end - e) {
        unsigned q = pk[e + s];
        acc += pk_w(q) * bf2f(tmpc[(size_t)pk_c(q) * 16 + f]);
    }
    acc += __shfl_xor(acc, 16);
    acc += __shfl_xor(acc, 32);
    float v = acc + bias[f];

    float m = v;
#pragma unroll
    for (int off = 1; off < 16; off <<= 1) m = fmaxf(m, __shfl_xor(m, off, 16));
    float sum = expf(v - m);
#pragma unroll
    for (int off = 1; off < 16; off <<= 1) sum += __shfl_xor(sum, off, 16);
    float ls = logf(sum);
    if (lane < 16) {
        e5[(size_t)r * 16 + f] = v;
        out0[(size_t)r * 16 + f] = v - m - ls;
    }
}

// ---------------- launch ----------------

extern "C" void kernel_launch(void* const* d_in, const int* in_sizes, int n_in,
                              void* d_out, int out_size, void* d_ws, size_t ws_size,
                              hipStream_t stream) {
    const float* x = (const float*)d_in[0];
    const int* erow = (const int*)d_in[1];
    const int* ecol = (const int*)d_in[2];
    const float* ew = (const float*)d_in[3];
    const float* W1 = (const float*)d_in[4];
    const float* b1 = (const float*)d_in[5];
    const float* W2 = (const float*)d_in[6];
    const float* b2 = (const float*)d_in[7];
    const float* W3 = (const float*)d_in[8];
    const float* b3 = (const float*)d_in[9];
    const float* W4 = (const float*)d_in[10];
    const float* b4 = (const float*)d_in[11];
    const float* W5 = (const float*)d_in[12];
    const float* b5 = (const float*)d_in[13];

    // Output layout: log_softmax(e5), e1, e2, e3, e4, e5
    float* out0 = (float*)d_out;
    float* e1 = out0 + (size_t)NN * NCLASS;
    float* e2 = e1 + (size_t)NN * NHID;
    float* e3 = e2 + (size_t)NN * NHID;
    float* e4 = e3 + (size_t)NN * NHID;
    float* e5 = e4 + (size_t)NN * NHID;

    // Workspace layout
    char* ws = (char*)d_ws;
    unsigned short* tmpA = (unsigned short*)ws; ws += (size_t)NN * NHID * 2;   // 6.4 MB
    unsigned short* tmpB = (unsigned short*)ws; ws += (size_t)NN * NHID * 2;   // 6.4 MB
    unsigned short* tmpc = (unsigned short*)ws; ws += ((size_t)NN * NCLASS * 2 + 255) / 256 * 256;  // 1.6 MB
    int* qcur = (int*)ws;     ws += 256;                                       // 8 queue tickets (zeroed)
    int* deg = (int*)ws;      ws += ((size_t)NN * 4 + 255) / 256 * 256;        // zeroed below
    int* row_ptr = (int*)ws;  ws += ((size_t)(NN + 1) * 4 + 255) / 256 * 256;
    int* blocksum = (int*)ws; ws += ((size_t)NB_SCAN * 4 + 255) / 256 * 256;
    uint2* rr8 = (uint2*)ws;  ws += (size_t)NE * 8;                            // 6.4 MB packed records
    unsigned* pk = (unsigned*)ws; ws += (size_t)NE * 4;                        // 3.2 MB packed edges

    // ---- CSR build: pack+rank, scans, XCD-affine rank scatter ----
    hipMemsetAsync(qcur, 0, 256 + (size_t)NN * 4, stream);  // qcur + deg (contiguous)
    hist_pack_kernel<<<(NE + 255) / 256, 256, 0, stream>>>(erow, ecol, ew, deg, rr8, NE);
    scan_sum_kernel<<<NB_SCAN, 256, 0, stream>>>(deg, blocksum, NN);
    scan_final_kernel<<<NB_SCAN, 256, 0, stream>>>(deg, blocksum, row_ptr, NN);
    scatter8_kernel<<<8 * SC_CHUNKS, 256, 0, stream>>>(rr8, row_ptr, qcur, pk, NE);

    // ---- Layer 1 dense: tmpA = x @ W1 (bf16) ----
    gemm64_kernel<NFEAT, false><<<GB, 256, 0, stream>>>(x, W1, tmpA, NN);

    // ---- Layers 1-4: fused SpMM + next dense GEMM ----
    const int FG = NN / 8;  // 6250 blocks x 8 rows
    spmm64_fused_kernel<64><<<FG, 512, 0, stream>>>(tmpA, row_ptr, pk, b1, W2, e1, tmpB, NN);
    spmm64_fused_kernel<64><<<FG, 512, 0, stream>>>(tmpB, row_ptr, pk, b2, W3, e2, tmpA, NN);
    spmm64_fused_kernel<64><<<FG, 512, 0, stream>>>(tmpA, row_ptr, pk, b3, W4, e3, tmpB, NN);
    spmm64_fused_kernel<16><<<FG, 512, 0, stream>>>(tmpB, row_ptr, pk, b4, W5, e4, tmpc, NN);

    // ---- Layer 5: SpMM(F=16) fused with log_softmax ----
    spmm16_lsm_kernel<<<(NN + 3) / 4, 256, 0, stream>>>(tmpc, row_ptr, pk, b5, e5, out0, NN);
}

// Round 6
// 380.419 us; speedup vs baseline: 1.2134x; 1.2134x over previous
//
#include <hip/hip_runtime.h>
#include <math.h>

// Problem constants (from reference)
#define NN 50000
#define NE 800000
#define NFEAT 128
#define NHID 64
#define NCLASS 16
#define NB_SCAN ((NN + 255) / 256)  // 196
#define GB ((NN + 63) / 64)         // 782 row-tiles for layer-1 GEMM
#define SGRP 4                      // scatter destination groups
#define ROWS_PER_SGRP ((NN + SGRP - 1) / SGRP)  // 12500
#define SCHUNKS 392                 // scatter chunks per group

// fp32 <-> bf16 helpers (RNE round)
__device__ inline unsigned short f2bf(float f) {
    unsigned u = __builtin_bit_cast(unsigned, f);
    u += 0x7fffu + ((u >> 16) & 1u);
    return (unsigned short)(u >> 16);
}
__device__ inline float bf2f(unsigned short h) {
    return __builtin_bit_cast(float, (unsigned)h << 16);
}
// Packed edge: low 16 = col (NN < 65536), high 16 = weight as bf16.
__device__ inline float pk_w(unsigned v) { return bf2f((unsigned short)(v >> 16)); }
__device__ inline int pk_c(unsigned v) { return (int)(v & 0xffffu); }

// ---------------- CSR build ----------------

// Pack + rank: atomicAdd's return value IS the edge's rank within its row.
// rr8.x = row<<16 | rank ; rr8.y = wbf16<<16 | col  (== final pk word).
__global__ __launch_bounds__(256) void hist_pack_kernel(const int* __restrict__ erow,
                                                        const int* __restrict__ ecol,
                                                        const float* __restrict__ ew,
                                                        int* __restrict__ deg,
                                                        uint2* __restrict__ rr8, int E) {
    int e = blockIdx.x * 256 + threadIdx.x;
    if (e < E) {
        int r = erow[e];
        int k = atomicAdd(&deg[r], 1);
        uint2 v;
        v.x = ((unsigned)r << 16) | (unsigned)k;
        v.y = ((unsigned)f2bf(ew[e]) << 16) | (unsigned)ecol[e];
        rr8[e] = v;
    }
}

__global__ __launch_bounds__(256) void scan_sum_kernel(const int* __restrict__ deg,
                                                       int* __restrict__ blocksum, int n) {
    __shared__ int s[256];
    const int t = threadIdx.x;
    int i = blockIdx.x * 256 + t;
    s[t] = (i < n) ? deg[i] : 0;
    __syncthreads();
#pragma unroll
    for (int off = 128; off > 0; off >>= 1) {
        if (t < off) s[t] += s[t + off];
        __syncthreads();
    }
    if (t == 0) blocksum[blockIdx.x] = s[0];
}

// Merged top-level + final scan: each block scans the 196 block-sums in LDS itself.
__global__ __launch_bounds__(256) void scan_final_kernel(const int* __restrict__ deg,
                                                         const int* __restrict__ blocksum,
                                                         int* __restrict__ row_ptr, int n) {
    __shared__ int bs[256];
    __shared__ int s[256];
    const int t = threadIdx.x;
    bs[t] = (t < NB_SCAN) ? blocksum[t] : 0;
    __syncthreads();
    for (int off = 1; off < 256; off <<= 1) {
        int u = (t >= off) ? bs[t - off] : 0;
        __syncthreads();
        bs[t] += u;
        __syncthreads();
    }
    const int blockpre = (blockIdx.x == 0) ? 0 : bs[blockIdx.x - 1];

    int i = blockIdx.x * 256 + t;
    int d = (i < n) ? deg[i] : 0;
    s[t] = d;
    __syncthreads();
    for (int off = 1; off < 256; off <<= 1) {
        int u = (t >= off) ? s[t - off] : 0;
        __syncthreads();
        s[t] += u;
        __syncthreads();
    }
    int excl = blockpre + s[t] - d;
    if (i < n) {
        row_ptr[i] = excl;
        if (i == n - 1) row_ptr[n] = excl + d;
    }
}

// Static partitioned rank-scatter (the scheme the 344us baseline validated):
// group g = blockIdx&3 owns rows [g*12500, (g+1)*12500); each chunk streams its
// slice of rr8 and writes only its group's rows -> destination region is
// small + group-local, no atomics, no queues. rr8 re-read SGRP times (25.6 MB).
__global__ __launch_bounds__(256) void scatter_rank8_kernel(const uint2* __restrict__ rr8,
                                                            const int* __restrict__ row_ptr,
                                                            unsigned* __restrict__ pk, int E) {
    const int g = blockIdx.x & (SGRP - 1);
    const int chunk = blockIdx.x / SGRP;
    const int CH = (E + SCHUNKS - 1) / SCHUNKS;
    const int lo = chunk * CH;
    const int hi = (lo + CH < E) ? lo + CH : E;
    const int rlo = g * ROWS_PER_SGRP;
    const int rhi = (rlo + ROWS_PER_SGRP < NN) ? rlo + ROWS_PER_SGRP : NN;
    for (int e = lo + threadIdx.x; e < hi; e += 256) {
        uint2 v = rr8[e];
        int r = (int)(v.x >> 16);
        if (r >= rlo && r < rhi) {
            pk[row_ptr[r] + (int)(v.x & 0xffffu)] = v.y;
        }
    }
}

// ---------------- Layer-1 GEMM: out[M,64] = in[M,128] @ W[128,64], bf16 out ----------------
template <int K, bool RELU_IN>
__global__ __launch_bounds__(256) void gemm64_kernel(const float* __restrict__ in,
                                                     const float* __restrict__ Wg,
                                                     unsigned short* __restrict__ outb, int M) {
    constexpr int KC = 64;
    __shared__ float xs[KC][68];
    __shared__ float Ws[KC][64];
    const int t = threadIdx.x;
    const int tx = t % 16;
    const int ty = t / 16;
    const int r0 = blockIdx.x * 64;

    float acc[4][4];
#pragma unroll
    for (int i = 0; i < 4; i++)
#pragma unroll
        for (int j = 0; j < 4; j++) acc[i][j] = 0.f;

    for (int k0 = 0; k0 < K; k0 += KC) {
        for (int i = t * 4; i < KC * 64; i += 1024) {
            *(float4*)&Ws[i / 64][i % 64] = *(const float4*)&Wg[(size_t)k0 * 64 + i];
        }
        {
            const int r = t / 4;
            const int q = t % 4;
            const int gr = r0 + r;
#pragma unroll
            for (int i = 0; i < 4; i++) {
                int k = q * 16 + i * 4;
                float4 v;
                if (gr < M)
                    v = *(const float4*)&in[(size_t)gr * K + k0 + k];
                else
                    v = make_float4(0.f, 0.f, 0.f, 0.f);
                if (RELU_IN) {
                    v.x = fmaxf(v.x, 0.f);
                    v.y = fmaxf(v.y, 0.f);
                    v.z = fmaxf(v.z, 0.f);
                    v.w = fmaxf(v.w, 0.f);
                }
                xs[k + 0][r] = v.x;
                xs[k + 1][r] = v.y;
                xs[k + 2][r] = v.z;
                xs[k + 3][r] = v.w;
            }
        }
        __syncthreads();
#pragma unroll 8
        for (int k = 0; k < KC; k++) {
            float4 xv = *(const float4*)&xs[k][ty * 4];
            float4 wv = *(const float4*)&Ws[k][tx * 4];
            acc[0][0] += xv.x * wv.x; acc[0][1] += xv.x * wv.y;
            acc[0][2] += xv.x * wv.z; acc[0][3] += xv.x * wv.w;
            acc[1][0] += xv.y * wv.x; acc[1][1] += xv.y * wv.y;
            acc[1][2] += xv.y * wv.z; acc[1][3] += xv.y * wv.w;
            acc[2][0] += xv.z * wv.x; acc[2][1] += xv.z * wv.y;
            acc[2][2] += xv.z * wv.z; acc[2][3] += xv.z * wv.w;
            acc[3][0] += xv.w * wv.x; acc[3][1] += xv.w * wv.y;
            acc[3][2] += xv.w * wv.z; acc[3][3] += xv.w * wv.w;
        }
        __syncthreads();
    }
#pragma unroll
    for (int i = 0; i < 4; i++) {
        int r = r0 + ty * 4 + i;
        if (r < M) {
            ushort4 u;
            u.x = f2bf(acc[i][0]);
            u.y = f2bf(acc[i][1]);
            u.z = f2bf(acc[i][2]);
            u.w = f2bf(acc[i][3]);
            *(ushort4*)&outb[(size_t)r * 64 + tx * 4] = u;
        }
    }
}

// ---------------- Fused SpMM(F=64) + next-layer dense GEMM, paired-edge gather ----------------
// One row per wave64. Lane-half h (0/1) processes edges e+2k+h; each lane loads
// a ushort2 feature-pair (f=2*(lane&31)) -> 16 edges in flight per unroll batch
// (2x the old MLP), half the gather instructions per edge, tail <= 1 edge.
// Cross-half reduce via shfl_xor(32). Epilogue: 8 rows -> LDS, relu, @W -> bf16.
template <int NOUT>
__global__ __launch_bounds__(512) void spmm64_fused_kernel(
    const unsigned short* __restrict__ gb,   // gather source [*,64] bf16
    const int* __restrict__ row_ptr,
    const unsigned* __restrict__ pk,
    const float* __restrict__ bias,
    const float* __restrict__ Wn,            // [64, NOUT] fp32 (next layer)
    float* __restrict__ e_out,               // [M,64] fp32 (required output)
    unsigned short* __restrict__ nxt,        // [M,NOUT] bf16 (next layer input)
    int M) {
    __shared__ float Wlt[NOUT][65];          // transposed: Wlt[j][k]
    __shared__ float xs[8][64];
    const int t = threadIdx.x;

    for (int idx = t; idx < 64 * NOUT; idx += 512) {
        int k = idx / NOUT, j = idx % NOUT;
        Wlt[j][k] = Wn[idx];
    }

    const int wv = __builtin_amdgcn_readfirstlane(t >> 6);  // wave id 0..7 (uniform)
    const int lane = t & 63;
    const int h = lane >> 5;        // edge-parity half
    const int f = (lane & 31) * 2;  // feature pair
    int r = blockIdx.x * 8 + wv;
    if (r >= M) r = M - 1;  // defensive; grid sized exactly (50000/8)

    float a0 = 0.f, a1 = 0.f;
    int e = row_ptr[r];
    const int end = row_ptr[r + 1];
    for (; e + 16 <= end; e += 16) {
        unsigned q0 = pk[e + 0 + h], q1 = pk[e + 2 + h], q2 = pk[e + 4 + h], q3 = pk[e + 6 + h];
        unsigned q4 = pk[e + 8 + h], q5 = pk[e + 10 + h], q6 = pk[e + 12 + h], q7 = pk[e + 14 + h];
        unsigned g0 = *(const unsigned*)&gb[(size_t)pk_c(q0) * 64 + f];
        unsigned g1 = *(const unsigned*)&gb[(size_t)pk_c(q1) * 64 + f];
        unsigned g2 = *(const unsigned*)&gb[(size_t)pk_c(q2) * 64 + f];
        unsigned g3 = *(const unsigned*)&gb[(size_t)pk_c(q3) * 64 + f];
        unsigned g4 = *(const unsigned*)&gb[(size_t)pk_c(q4) * 64 + f];
        unsigned g5 = *(const unsigned*)&gb[(size_t)pk_c(q5) * 64 + f];
        unsigned g6 = *(const unsigned*)&gb[(size_t)pk_c(q6) * 64 + f];
        unsigned g7 = *(const unsigned*)&gb[(size_t)pk_c(q7) * 64 + f];
        float w;
        w = pk_w(q0); a0 += w * bf2f((unsigned short)(g0 & 0xffffu)); a1 += w * bf2f((unsigned short)(g0 >> 16));
        w = pk_w(q1); a0 += w * bf2f((unsigned short)(g1 & 0xffffu)); a1 += w * bf2f((unsigned short)(g1 >> 16));
        w = pk_w(q2); a0 += w * bf2f((unsigned short)(g2 & 0xffffu)); a1 += w * bf2f((unsigned short)(g2 >> 16));
        w = pk_w(q3); a0 += w * bf2f((unsigned short)(g3 & 0xffffu)); a1 += w * bf2f((unsigned short)(g3 >> 16));
        w = pk_w(q4); a0 += w * bf2f((unsigned short)(g4 & 0xffffu)); a1 += w * bf2f((unsigned short)(g4 >> 16));
        w = pk_w(q5); a0 += w * bf2f((unsigned short)(g5 & 0xffffu)); a1 += w * bf2f((unsigned short)(g5 >> 16));
        w = pk_w(q6); a0 += w * bf2f((unsigned short)(g6 & 0xffffu)); a1 += w * bf2f((unsigned short)(g6 >> 16));
        w = pk_w(q7); a0 += w * bf2f((unsigned short)(g7 & 0xffffu)); a1 += w * bf2f((unsigned short)(g7 >> 16));
    }
    for (; e + 2 <= end; e += 2) {
        unsigned q = pk[e + h];
        unsigned g = *(const unsigned*)&gb[(size_t)pk_c(q) * 64 + f];
        float w = pk_w(q);
        a0 += w * bf2f((unsigned short)(g & 0xffffu));
        a1 += w * bf2f((unsigned short)(g >> 16));
    }
    if (e < end && h == 0) {  // single leftover edge: half 0 only
        unsigned q = pk[e];
        unsigned g = *(const unsigned*)&gb[(size_t)pk_c(q) * 64 + f];
        float w = pk_w(q);
        a0 += w * bf2f((unsigned short)(g & 0xffffu));
        a1 += w * bf2f((unsigned short)(g >> 16));
    }
    // combine the two edge-parity halves (lane & lane^32 hold same feature pair)
    a0 += __shfl_xor(a0, 32);
    a1 += __shfl_xor(a1, 32);
    float2 v;
    v.x = a0 + bias[f];
    v.y = a1 + bias[f + 1];
    if (h == 0) {
        *(float2*)&e_out[(size_t)r * 64 + f] = v;
        xs[wv][f] = fmaxf(v.x, 0.f);
        xs[wv][f + 1] = fmaxf(v.y, 0.f);
    }
    __syncthreads();

    // Epilogue GEMM: nxt[r][j] = sum_k relu(e[r][k]) * W[k][j]
    if (NOUT == 64) {
        const int rr = t >> 6;   // wave-uniform -> xs reads broadcast (free)
        const int j = t & 63;
        float acc = 0.f;
#pragma unroll 16
        for (int k = 0; k < 64; k++) acc += xs[rr][k] * Wlt[j][k];
        int gr = blockIdx.x * 8 + rr;
        if (gr < M) nxt[(size_t)gr * 64 + j] = f2bf(acc);
    } else {
        if (t < 8 * NOUT) {
            const int rr = t / NOUT;
            const int j = t % NOUT;
            float acc = 0.f;
#pragma unroll 16
            for (int k = 0; k < 64; k++) acc += xs[rr][k] * Wlt[j][k];
            int gr = blockIdx.x * 8 + rr;
            if (gr < M) nxt[(size_t)gr * NOUT + j] = f2bf(acc);
        }
    }
}

// ---------------- SpMM (F=16) fused with log_softmax ----------------
// One row per wave64: lane = 16*slot + f, 4 edge slots in parallel, shfl-reduce.
__global__ __launch_bounds__(256) void spmm16_lsm_kernel(const unsigned short* __restrict__ tmpc,
                                                         const int* __restrict__ row_ptr,
                                                         const unsigned* __restrict__ pk,
                                                         const float* __restrict__ bias,
                                                         float* __restrict__ e5,
                                                         float* __restrict__ out0, int M) {
    const int t = threadIdx.x;
    const int wv = __builtin_amdgcn_readfirstlane(t >> 6);  // wave 0..3
    const int lane = t & 63;
    const int f = lane & 15;
    const int s = lane >> 4;  // slot 0..3
    const int r = blockIdx.x * 4 + wv;
    if (r >= M) return;

    int e = row_ptr[r];
    const int end = row_ptr[r + 1];
    float acc = 0.f;
    for (; e + 8 <= end; e += 8) {
        unsigned qa = pk[e + s];
        unsigned qb = pk[e + 4 + s];
        acc += pk_w(qa) * bf2f(tmpc[(size_t)pk_c(qa) * 16 + f]);
        acc += pk_w(qb) * bf2f(tmpc[(size_t)pk_c(qb) * 16 + f]);
    }
    if (e + 4 <= end) {
        unsigned q = pk[e + s];
        acc += pk_w(q) * bf2f(tmpc[(size_t)pk_c(q) * 16 + f]);
        e += 4;
    }
    if (s < end - e) {
        unsigned q = pk[e + s];
        acc += pk_w(q) * bf2f(tmpc[(size_t)pk_c(q) * 16 + f]);
    }
    acc += __shfl_xor(acc, 16);
    acc += __shfl_xor(acc, 32);
    float v = acc + bias[f];

    float m = v;
#pragma unroll
    for (int off = 1; off < 16; off <<= 1) m = fmaxf(m, __shfl_xor(m, off, 16));
    float sum = expf(v - m);
#pragma unroll
    for (int off = 1; off < 16; off <<= 1) sum += __shfl_xor(sum, off, 16);
    float ls = logf(sum);
    if (lane < 16) {
        e5[(size_t)r * 16 + f] = v;
        out0[(size_t)r * 16 + f] = v - m - ls;
    }
}

// ---------------- launch ----------------

extern "C" void kernel_launch(void* const* d_in, const int* in_sizes, int n_in,
                              void* d_out, int out_size, void* d_ws, size_t ws_size,
                              hipStream_t stream) {
    const float* x = (const float*)d_in[0];
    const int* erow = (const int*)d_in[1];
    const int* ecol = (const int*)d_in[2];
    const float* ew = (const float*)d_in[3];
    const float* W1 = (const float*)d_in[4];
    const float* b1 = (const float*)d_in[5];
    const float* W2 = (const float*)d_in[6];
    const float* b2 = (const float*)d_in[7];
    const float* W3 = (const float*)d_in[8];
    const float* b3 = (const float*)d_in[9];
    const float* W4 = (const float*)d_in[10];
    const float* b4 = (const float*)d_in[11];
    const float* W5 = (const float*)d_in[12];
    const float* b5 = (const float*)d_in[13];

    // Output layout: log_softmax(e5), e1, e2, e3, e4, e5
    float* out0 = (float*)d_out;
    float* e1 = out0 + (size_t)NN * NCLASS;
    float* e2 = e1 + (size_t)NN * NHID;
    float* e3 = e2 + (size_t)NN * NHID;
    float* e4 = e3 + (size_t)NN * NHID;
    float* e5 = e4 + (size_t)NN * NHID;

    // Workspace layout
    char* ws = (char*)d_ws;
    unsigned short* tmpA = (unsigned short*)ws; ws += (size_t)NN * NHID * 2;   // 6.4 MB
    unsigned short* tmpB = (unsigned short*)ws; ws += (size_t)NN * NHID * 2;   // 6.4 MB
    unsigned short* tmpc = (unsigned short*)ws; ws += ((size_t)NN * NCLASS * 2 + 255) / 256 * 256;  // 1.6 MB
    int* deg = (int*)ws;      ws += ((size_t)NN * 4 + 255) / 256 * 256;        // zeroed below
    int* row_ptr = (int*)ws;  ws += ((size_t)(NN + 1) * 4 + 255) / 256 * 256;
    int* blocksum = (int*)ws; ws += ((size_t)NB_SCAN * 4 + 255) / 256 * 256;
    uint2* rr8 = (uint2*)ws;  ws += (size_t)NE * 8;                            // 6.4 MB packed records
    unsigned* pk = (unsigned*)ws; ws += (size_t)NE * 4;                        // 3.2 MB packed edges

    // ---- CSR build: pack+rank, scans, static partitioned rank-scatter ----
    hipMemsetAsync(deg, 0, (size_t)NN * 4, stream);
    hist_pack_kernel<<<(NE + 255) / 256, 256, 0, stream>>>(erow, ecol, ew, deg, rr8, NE);
    scan_sum_kernel<<<NB_SCAN, 256, 0, stream>>>(deg, blocksum, NN);
    scan_final_kernel<<<NB_SCAN, 256, 0, stream>>>(deg, blocksum, row_ptr, NN);
    scatter_rank8_kernel<<<SGRP * SCHUNKS, 256, 0, stream>>>(rr8, row_ptr, pk, NE);

    // ---- Layer 1 dense: tmpA = x @ W1 (bf16) ----
    gemm64_kernel<NFEAT, false><<<GB, 256, 0, stream>>>(x, W1, tmpA, NN);

    // ---- Layers 1-4: fused SpMM + next dense GEMM ----
    const int FG = NN / 8;  // 6250 blocks x 8 rows
    spmm64_fused_kernel<64><<<FG, 512, 0, stream>>>(tmpA, row_ptr, pk, b1, W2, e1, tmpB, NN);
    spmm64_fused_kernel<64><<<FG, 512, 0, stream>>>(tmpB, row_ptr, pk, b2, W3, e2, tmpA, NN);
    spmm64_fused_kernel<64><<<FG, 512, 0, stream>>>(tmpA, row_ptr, pk, b3, W4, e3, tmpB, NN);
    spmm64_fused_kernel<16><<<FG, 512, 0, stream>>>(tmpB, row_ptr, pk, b4, W5, e4, tmpc, NN);

    // ---- Layer 5: SpMM(F=16) fused with log_softmax ----
    spmm16_lsm_kernel<<<(NN + 3) / 4, 256, 0, stream>>>(tmpc, row_ptr, pk, b5, e5, out0, NN);
}

// Round 8
// 348.222 us; speedup vs baseline: 1.3256x; 1.0925x over previous
//
#include <hip/hip_runtime.h>
#include <math.h>

// Problem constants (from reference)
#define NN 50000
#define NE 800000
#define NFEAT 128
#define NHID 64
#define NCLASS 16
#define NB_SCAN ((NN + 255) / 256)  // 196
#define GB ((NN + 63) / 64)         // 782 row-tiles for layer-1 GEMM
#define SGRP 4                      // scatter destination groups
#define ROWS_PER_SGRP ((NN + SGRP - 1) / SGRP)  // 12500
#define SCHUNKS 392                 // scatter chunks per group

// fp32 <-> bf16 helpers (RNE round)
__device__ inline unsigned short f2bf(float f) {
    unsigned u = __builtin_bit_cast(unsigned, f);
    u += 0x7fffu + ((u >> 16) & 1u);
    return (unsigned short)(u >> 16);
}
__device__ inline float bf2f(unsigned short h) {
    return __builtin_bit_cast(float, (unsigned)h << 16);
}
// Packed edge: low 16 = col (NN < 65536), high 16 = weight as bf16.
__device__ inline float pk_w(unsigned v) { return bf2f((unsigned short)(v >> 16)); }
__device__ inline int pk_c(unsigned v) { return (int)(v & 0xffffu); }

// ---------------- CSR build ----------------

// Pack + rank: atomicAdd's return value IS the edge's rank within its row.
// rr8.x = row<<16 | rank ; rr8.y = wbf16<<16 | col  (== final pk word).
__global__ __launch_bounds__(256) void hist_pack_kernel(const int* __restrict__ erow,
                                                        const int* __restrict__ ecol,
                                                        const float* __restrict__ ew,
                                                        int* __restrict__ deg,
                                                        uint2* __restrict__ rr8, int E) {
    int e = blockIdx.x * 256 + threadIdx.x;
    if (e < E) {
        int r = erow[e];
        int k = atomicAdd(&deg[r], 1);
        uint2 v;
        v.x = ((unsigned)r << 16) | (unsigned)k;
        v.y = ((unsigned)f2bf(ew[e]) << 16) | (unsigned)ecol[e];
        rr8[e] = v;
    }
}

__global__ __launch_bounds__(256) void scan_sum_kernel(const int* __restrict__ deg,
                                                       int* __restrict__ blocksum, int n) {
    __shared__ int s[256];
    const int t = threadIdx.x;
    int i = blockIdx.x * 256 + t;
    s[t] = (i < n) ? deg[i] : 0;
    __syncthreads();
#pragma unroll
    for (int off = 128; off > 0; off >>= 1) {
        if (t < off) s[t] += s[t + off];
        __syncthreads();
    }
    if (t == 0) blocksum[blockIdx.x] = s[0];
}

// Merged top-level + final scan: each block scans the 196 block-sums in LDS itself.
__global__ __launch_bounds__(256) void scan_final_kernel(const int* __restrict__ deg,
                                                         const int* __restrict__ blocksum,
                                                         int* __restrict__ row_ptr, int n) {
    __shared__ int bs[256];
    __shared__ int s[256];
    const int t = threadIdx.x;
    bs[t] = (t < NB_SCAN) ? blocksum[t] : 0;
    __syncthreads();
    for (int off = 1; off < 256; off <<= 1) {
        int u = (t >= off) ? bs[t - off] : 0;
        __syncthreads();
        bs[t] += u;
        __syncthreads();
    }
    const int blockpre = (blockIdx.x == 0) ? 0 : bs[blockIdx.x - 1];

    int i = blockIdx.x * 256 + t;
    int d = (i < n) ? deg[i] : 0;
    s[t] = d;
    __syncthreads();
    for (int off = 1; off < 256; off <<= 1) {
        int u = (t >= off) ? s[t - off] : 0;
        __syncthreads();
        s[t] += u;
        __syncthreads();
    }
    int excl = blockpre + s[t] - d;
    if (i < n) {
        row_ptr[i] = excl;
        if (i == n - 1) row_ptr[n] = excl + d;
    }
}

// Static partitioned rank-scatter: group g = blockIdx&3 owns rows
// [g*12500,(g+1)*12500); each chunk streams its slice of rr8 and writes only
// its group's rows -> destination region small + group-local, no atomics.
__global__ __launch_bounds__(256) void scatter_rank8_kernel(const uint2* __restrict__ rr8,
                                                            const int* __restrict__ row_ptr,
                                                            unsigned* __restrict__ pk, int E) {
    const int g = blockIdx.x & (SGRP - 1);
    const int chunk = blockIdx.x / SGRP;
    const int CH = (E + SCHUNKS - 1) / SCHUNKS;
    const int lo = chunk * CH;
    const int hi = (lo + CH < E) ? lo + CH : E;
    const int rlo = g * ROWS_PER_SGRP;
    const int rhi = (rlo + ROWS_PER_SGRP < NN) ? rlo + ROWS_PER_SGRP : NN;
    for (int e = lo + threadIdx.x; e < hi; e += 256) {
        uint2 v = rr8[e];
        int r = (int)(v.x >> 16);
        if (r >= rlo && r < rhi) {
            pk[row_ptr[r] + (int)(v.x & 0xffffu)] = v.y;
        }
    }
}

// ---------------- Layer-1 GEMM: out[M,64] = in[M,128] @ W[128,64], bf16 out ----------------
template <int K, bool RELU_IN>
__global__ __launch_bounds__(256) void gemm64_kernel(const float* __restrict__ in,
                                                     const float* __restrict__ Wg,
                                                     unsigned short* __restrict__ outb, int M) {
    constexpr int KC = 64;
    __shared__ float xs[KC][68];
    __shared__ float Ws[KC][64];
    const int t = threadIdx.x;
    const int tx = t % 16;
    const int ty = t / 16;
    const int r0 = blockIdx.x * 64;

    float acc[4][4];
#pragma unroll
    for (int i = 0; i < 4; i++)
#pragma unroll
        for (int j = 0; j < 4; j++) acc[i][j] = 0.f;

    for (int k0 = 0; k0 < K; k0 += KC) {
        for (int i = t * 4; i < KC * 64; i += 1024) {
            *(float4*)&Ws[i / 64][i % 64] = *(const float4*)&Wg[(size_t)k0 * 64 + i];
        }
        {
            const int r = t / 4;
            const int q = t % 4;
            const int gr = r0 + r;
#pragma unroll
            for (int i = 0; i < 4; i++) {
                int k = q * 16 + i * 4;
                float4 v;
                if (gr < M)
                    v = *(const float4*)&in[(size_t)gr * K + k0 + k];
                else
                    v = make_float4(0.f, 0.f, 0.f, 0.f);
                if (RELU_IN) {
                    v.x = fmaxf(v.x, 0.f);
                    v.y = fmaxf(v.y, 0.f);
                    v.z = fmaxf(v.z, 0.f);
                    v.w = fmaxf(v.w, 0.f);
                }
                xs[k + 0][r] = v.x;
                xs[k + 1][r] = v.y;
                xs[k + 2][r] = v.z;
                xs[k + 3][r] = v.w;
            }
        }
        __syncthreads();
#pragma unroll 8
        for (int k = 0; k < KC; k++) {
            float4 xv = *(const float4*)&xs[k][ty * 4];
            float4 wv = *(const float4*)&Ws[k][tx * 4];
            acc[0][0] += xv.x * wv.x; acc[0][1] += xv.x * wv.y;
            acc[0][2] += xv.x * wv.z; acc[0][3] += xv.x * wv.w;
            acc[1][0] += xv.y * wv.x; acc[1][1] += xv.y * wv.y;
            acc[1][2] += xv.y * wv.z; acc[1][3] += xv.y * wv.w;
            acc[2][0] += xv.z * wv.x; acc[2][1] += xv.z * wv.y;
            acc[2][2] += xv.z * wv.z; acc[2][3] += xv.z * wv.w;
            acc[3][0] += xv.w * wv.x; acc[3][1] += xv.w * wv.y;
            acc[3][2] += xv.w * wv.z; acc[3][3] += xv.w * wv.w;
        }
        __syncthreads();
    }
#pragma unroll
    for (int i = 0; i < 4; i++) {
        int r = r0 + ty * 4 + i;
        if (r < M) {
            ushort4 u;
            u.x = f2bf(acc[i][0]);
            u.y = f2bf(acc[i][1]);
            u.z = f2bf(acc[i][2]);
            u.w = f2bf(acc[i][3]);
            *(ushort4*)&outb[(size_t)r * 64 + tx * 4] = u;
        }
    }
}

// ---------------- Fused SpMM(F=64) + next-layer dense GEMM ----------------
// Gather phase = the baseline-proven spmm64v2 structure: 2 rows per wave
// (32 lanes/row), each lane loads a ushort2 feature-pair, 8-edge batches ->
// 8 gather instrs x 8 cache lines in flight per wave; 256-thread blocks with
// 18.7KB LDS -> 8 blocks/CU (2048 threads) for max miss concurrency.
// Epilogue: block's 8 rows in LDS, relu, 8x64 @ W(64xNOUT) -> bf16 nxt buffer.
template <int NOUT>
__global__ __launch_bounds__(256) void spmm64_fused_kernel(
    const unsigned short* __restrict__ gb,   // gather source [*,64] bf16
    const int* __restrict__ row_ptr,
    const unsigned* __restrict__ pk,
    const float* __restrict__ bias,
    const float* __restrict__ Wn,            // [64, NOUT] fp32 (next layer)
    float* __restrict__ e_out,               // [M,64] fp32 (required output)
    unsigned short* __restrict__ nxt,        // [M,NOUT] bf16 (next layer input)
    int M) {
    __shared__ float Wlt[NOUT][65];          // transposed: Wlt[j][k]
    __shared__ float xs[8][64];
    const int t = threadIdx.x;

    // Cooperative W stage (transposed). Coalesced global read.
    for (int idx = t; idx < 64 * NOUT; idx += 256) {
        int k = idx / NOUT, j = idx % NOUT;
        Wlt[j][k] = Wn[idx];
    }

    const int rb = t >> 5;          // row-in-block 0..7 (half-wave granularity)
    const int f2 = (t & 31) * 2;    // feature pair
    const int r = blockIdx.x * 8 + rb;  // grid exact: 6250*8 == 50000 == M

    int e = row_ptr[r];
    const int end = row_ptr[r + 1];
    float a0 = 0.f, a1 = 0.f;
    for (; e + 7 < end; e += 8) {
        unsigned q0 = pk[e + 0], q1 = pk[e + 1], q2 = pk[e + 2], q3 = pk[e + 3];
        unsigned q4 = pk[e + 4], q5 = pk[e + 5], q6 = pk[e + 6], q7 = pk[e + 7];
        unsigned g0 = *(const unsigned*)&gb[(size_t)pk_c(q0) * 64 + f2];
        unsigned g1 = *(const unsigned*)&gb[(size_t)pk_c(q1) * 64 + f2];
        unsigned g2 = *(const unsigned*)&gb[(size_t)pk_c(q2) * 64 + f2];
        unsigned g3 = *(const unsigned*)&gb[(size_t)pk_c(q3) * 64 + f2];
        unsigned g4 = *(const unsigned*)&gb[(size_t)pk_c(q4) * 64 + f2];
        unsigned g5 = *(const unsigned*)&gb[(size_t)pk_c(q5) * 64 + f2];
        unsigned g6 = *(const unsigned*)&gb[(size_t)pk_c(q6) * 64 + f2];
        unsigned g7 = *(const unsigned*)&gb[(size_t)pk_c(q7) * 64 + f2];
        a0 += pk_w(q0) * bf2f((unsigned short)(g0 & 0xffffu));
        a1 += pk_w(q0) * bf2f((unsigned short)(g0 >> 16));
        a0 += pk_w(q1) * bf2f((unsigned short)(g1 & 0xffffu));
        a1 += pk_w(q1) * bf2f((unsigned short)(g1 >> 16));
        a0 += pk_w(q2) * bf2f((unsigned short)(g2 & 0xffffu));
        a1 += pk_w(q2) * bf2f((unsigned short)(g2 >> 16));
        a0 += pk_w(q3) * bf2f((unsigned short)(g3 & 0xffffu));
        a1 += pk_w(q3) * bf2f((unsigned short)(g3 >> 16));
        a0 += pk_w(q4) * bf2f((unsigned short)(g4 & 0xffffu));
        a1 += pk_w(q4) * bf2f((unsigned short)(g4 >> 16));
        a0 += pk_w(q5) * bf2f((unsigned short)(g5 & 0xffffu));
        a1 += pk_w(q5) * bf2f((unsigned short)(g5 >> 16));
        a0 += pk_w(q6) * bf2f((unsigned short)(g6 & 0xffffu));
        a1 += pk_w(q6) * bf2f((unsigned short)(g6 >> 16));
        a0 += pk_w(q7) * bf2f((unsigned short)(g7 & 0xffffu));
        a1 += pk_w(q7) * bf2f((unsigned short)(g7 >> 16));
    }
    for (; e < end; e++) {
        unsigned q = pk[e];
        unsigned g = *(const unsigned*)&gb[(size_t)pk_c(q) * 64 + f2];
        a0 += pk_w(q) * bf2f((unsigned short)(g & 0xffffu));
        a1 += pk_w(q) * bf2f((unsigned short)(g >> 16));
    }
    float2 v;
    v.x = a0 + bias[f2];
    v.y = a1 + bias[f2 + 1];
    *(float2*)&e_out[(size_t)r * 64 + f2] = v;
    xs[rb][f2] = fmaxf(v.x, 0.f);
    xs[rb][f2 + 1] = fmaxf(v.y, 0.f);
    __syncthreads();

    // Epilogue GEMM: nxt[r][j] = sum_k relu(e[r][k]) * W[k][j]
    if (NOUT == 64) {
        const int rblk = t >> 6;  // wave-uniform -> xs reads broadcast (free)
        const int j = t & 63;
        float acc0 = 0.f, acc1 = 0.f;
#pragma unroll 16
        for (int k = 0; k < 64; k++) {
            float w = Wlt[j][k];
            acc0 += xs[rblk][k] * w;
            acc1 += xs[rblk + 4][k] * w;
        }
        nxt[(size_t)(blockIdx.x * 8 + rblk) * 64 + j] = f2bf(acc0);
        nxt[(size_t)(blockIdx.x * 8 + rblk + 4) * 64 + j] = f2bf(acc1);
    } else {
        if (t < 8 * NOUT) {
            const int rr = t / NOUT;
            const int j = t % NOUT;
            float acc = 0.f;
#pragma unroll 16
            for (int k = 0; k < 64; k++) acc += xs[rr][k] * Wlt[j][k];
            nxt[(size_t)(blockIdx.x * 8 + rr) * NOUT + j] = f2bf(acc);
        }
    }
}

// ---------------- SpMM (F=16) fused with log_softmax ----------------
// One row per wave64: lane = 16*slot + f, 4 edge slots in parallel, shfl-reduce.
__global__ __launch_bounds__(256) void spmm16_lsm_kernel(const unsigned short* __restrict__ tmpc,
                                                         const int* __restrict__ row_ptr,
                                                         const unsigned* __restrict__ pk,
                                                         const float* __restrict__ bias,
                                                         float* __restrict__ e5,
                                                         float* __restrict__ out0, int M) {
    const int t = threadIdx.x;
    const int wv = __builtin_amdgcn_readfirstlane(t >> 6);  // wave 0..3
    const int lane = t & 63;
    const int f = lane & 15;
    const int s = lane >> 4;  // slot 0..3
    const int r = blockIdx.x * 4 + wv;
    if (r >= M) return;

    int e = row_ptr[r];
    const int end = row_ptr[r + 1];
    float acc = 0.f;
    for (; e + 8 <= end; e += 8) {
        unsigned qa = pk[e + s];
        unsigned qb = pk[e + 4 + s];
        acc += pk_w(qa) * bf2f(tmpc[(size_t)pk_c(qa) * 16 + f]);
        acc += pk_w(qb) * bf2f(tmpc[(size_t)pk_c(qb) * 16 + f]);
    }
    if (e + 4 <= end) {
        unsigned q = pk[e + s];
        acc += pk_w(q) * bf2f(tmpc[(size_t)pk_c(q) * 16 + f]);
        e += 4;
    }
    if (s < end - e) {
        unsigned q = pk[e + s];
        acc += pk_w(q) * bf2f(tmpc[(size_t)pk_c(q) * 16 + f]);
    }
    acc += __shfl_xor(acc, 16);
    acc += __shfl_xor(acc, 32);
    float v = acc + bias[f];

    float m = v;
#pragma unroll
    for (int off = 1; off < 16; off <<= 1) m = fmaxf(m, __shfl_xor(m, off, 16));
    float sum = expf(v - m);
#pragma unroll
    for (int off = 1; off < 16; off <<= 1) sum += __shfl_xor(sum, off, 16);
    float ls = logf(sum);
    if (lane < 16) {
        e5[(size_t)r * 16 + f] = v;
        out0[(size_t)r * 16 + f] = v - m - ls;
    }
}

// ---------------- launch ----------------

extern "C" void kernel_launch(void* const* d_in, const int* in_sizes, int n_in,
                              void* d_out, int out_size, void* d_ws, size_t ws_size,
                              hipStream_t stream) {
    const float* x = (const float*)d_in[0];
    const int* erow = (const int*)d_in[1];
    const int* ecol = (const int*)d_in[2];
    const float* ew = (const float*)d_in[3];
    const float* W1 = (const float*)d_in[4];
    const float* b1 = (const float*)d_in[5];
    const float* W2 = (const float*)d_in[6];
    const float* b2 = (const float*)d_in[7];
    const float* W3 = (const float*)d_in[8];
    const float* b3 = (const float*)d_in[9];
    const float* W4 = (const float*)d_in[10];
    const float* b4 = (const float*)d_in[11];
    const float* W5 = (const float*)d_in[12];
    const float* b5 = (const float*)d_in[13];

    // Output layout: log_softmax(e5), e1, e2, e3, e4, e5
    float* out0 = (float*)d_out;
    float* e1 = out0 + (size_t)NN * NCLASS;
    float* e2 = e1 + (size_t)NN * NHID;
    float* e3 = e2 + (size_t)NN * NHID;
    float* e4 = e3 + (size_t)NN * NHID;
    float* e5 = e4 + (size_t)NN * NHID;

    // Workspace layout
    char* ws = (char*)d_ws;
    unsigned short* tmpA = (unsigned short*)ws; ws += (size_t)NN * NHID * 2;   // 6.4 MB
    unsigned short* tmpB = (unsigned short*)ws; ws += (size_t)NN * NHID * 2;   // 6.4 MB
    unsigned short* tmpc = (unsigned short*)ws; ws += ((size_t)NN * NCLASS * 2 + 255) / 256 * 256;  // 1.6 MB
    int* deg = (int*)ws;      ws += ((size_t)NN * 4 + 255) / 256 * 256;        // zeroed below
    int* row_ptr = (int*)ws;  ws += ((size_t)(NN + 1) * 4 + 255) / 256 * 256;
    int* blocksum = (int*)ws; ws += ((size_t)NB_SCAN * 4 + 255) / 256 * 256;
    uint2* rr8 = (uint2*)ws;  ws += (size_t)NE * 8;                            // 6.4 MB packed records
    unsigned* pk = (unsigned*)ws; ws += (size_t)NE * 4;                        // 3.2 MB packed edges

    // ---- CSR build: pack+rank, scans, static partitioned rank-scatter ----
    hipMemsetAsync(deg, 0, (size_t)NN * 4, stream);
    hist_pack_kernel<<<(NE + 255) / 256, 256, 0, stream>>>(erow, ecol, ew, deg, rr8, NE);
    scan_sum_kernel<<<NB_SCAN, 256, 0, stream>>>(deg, blocksum, NN);
    scan_final_kernel<<<NB_SCAN, 256, 0, stream>>>(deg, blocksum, row_ptr, NN);
    scatter_rank8_kernel<<<SGRP * SCHUNKS, 256, 0, stream>>>(rr8, row_ptr, pk, NE);

    // ---- Layer 1 dense: tmpA = x @ W1 (bf16) ----
    gemm64_kernel<NFEAT, false><<<GB, 256, 0, stream>>>(x, W1, tmpA, NN);

    // ---- Layers 1-4: fused SpMM + next dense GEMM (256-thread blocks) ----
    const int FG = NN / 8;  // 6250 blocks x 8 rows
    spmm64_fused_kernel<64><<<FG, 256, 0, stream>>>(tmpA, row_ptr, pk, b1, W2, e1, tmpB, NN);
    spmm64_fused_kernel<64><<<FG, 256, 0, stream>>>(tmpB, row_ptr, pk, b2, W3, e2, tmpA, NN);
    spmm64_fused_kernel<64><<<FG, 256, 0, stream>>>(tmpA, row_ptr, pk, b3, W4, e3, tmpB, NN);
    spmm64_fused_kernel<16><<<FG, 256, 0, stream>>>(tmpB, row_ptr, pk, b4, W5, e4, tmpc, NN);

    // ---- Layer 5: SpMM(F=16) fused with log_softmax ----
    spmm16_lsm_kernel<<<(NN + 3) / 4, 256, 0, stream>>>(tmpc, row_ptr, pk, b5, e5, out0, NN);
}

// Round 9
// 306.881 us; speedup vs baseline: 1.5042x; 1.1347x over previous
//
#include <hip/hip_runtime.h>
#include <math.h>

// Problem constants (from reference)
#define NN 50000
#define NE 800000
#define NFEAT 128
#define NHID 64
#define NCLASS 16
#define NB_SCAN ((NN + 255) / 256)  // 196
#define GB ((NN + 63) / 64)         // 782 row-tiles for layer-1 GEMM
#define SGRP 4                      // scatter destination groups
#define ROWS_PER_SGRP ((NN + SGRP - 1) / SGRP)  // 12500
#define SCHUNKS 392                 // scatter chunks per group
#define EMAX 1024                   // LDS edge-stage capacity (mean/block = 128)

// fp32 <-> bf16 helpers (RNE round)
__device__ inline unsigned short f2bf(float f) {
    unsigned u = __builtin_bit_cast(unsigned, f);
    u += 0x7fffu + ((u >> 16) & 1u);
    return (unsigned short)(u >> 16);
}
__device__ inline float bf2f(unsigned short h) {
    return __builtin_bit_cast(float, (unsigned)h << 16);
}
// Packed edge: low 16 = col (NN < 65536), high 16 = weight as bf16.
__device__ inline float pk_w(unsigned v) { return bf2f((unsigned short)(v >> 16)); }
__device__ inline int pk_c(unsigned v) { return (int)(v & 0xffffu); }

// ---------------- CSR build ----------------

// Pack + rank: atomicAdd's return value IS the edge's rank within its row.
// rr8.x = row<<16 | rank ; rr8.y = wbf16<<16 | col  (== final pk word).
__global__ __launch_bounds__(256) void hist_pack_kernel(const int* __restrict__ erow,
                                                        const int* __restrict__ ecol,
                                                        const float* __restrict__ ew,
                                                        int* __restrict__ deg,
                                                        uint2* __restrict__ rr8, int E) {
    int e = blockIdx.x * 256 + threadIdx.x;
    if (e < E) {
        int r = erow[e];
        int k = atomicAdd(&deg[r], 1);
        uint2 v;
        v.x = ((unsigned)r << 16) | (unsigned)k;
        v.y = ((unsigned)f2bf(ew[e]) << 16) | (unsigned)ecol[e];
        rr8[e] = v;
    }
}

__global__ __launch_bounds__(256) void scan_sum_kernel(const int* __restrict__ deg,
                                                       int* __restrict__ blocksum, int n) {
    __shared__ int s[256];
    const int t = threadIdx.x;
    int i = blockIdx.x * 256 + t;
    s[t] = (i < n) ? deg[i] : 0;
    __syncthreads();
#pragma unroll
    for (int off = 128; off > 0; off >>= 1) {
        if (t < off) s[t] += s[t + off];
        __syncthreads();
    }
    if (t == 0) blocksum[blockIdx.x] = s[0];
}

// Merged top-level + final scan: each block scans the 196 block-sums in LDS itself.
__global__ __launch_bounds__(256) void scan_final_kernel(const int* __restrict__ deg,
                                                         const int* __restrict__ blocksum,
                                                         int* __restrict__ row_ptr, int n) {
    __shared__ int bs[256];
    __shared__ int s[256];
    const int t = threadIdx.x;
    bs[t] = (t < NB_SCAN) ? blocksum[t] : 0;
    __syncthreads();
    for (int off = 1; off < 256; off <<= 1) {
        int u = (t >= off) ? bs[t - off] : 0;
        __syncthreads();
        bs[t] += u;
        __syncthreads();
    }
    const int blockpre = (blockIdx.x == 0) ? 0 : bs[blockIdx.x - 1];

    int i = blockIdx.x * 256 + t;
    int d = (i < n) ? deg[i] : 0;
    s[t] = d;
    __syncthreads();
    for (int off = 1; off < 256; off <<= 1) {
        int u = (t >= off) ? s[t - off] : 0;
        __syncthreads();
        s[t] += u;
        __syncthreads();
    }
    int excl = blockpre + s[t] - d;
    if (i < n) {
        row_ptr[i] = excl;
        if (i == n - 1) row_ptr[n] = excl + d;
    }
}

// Static partitioned rank-scatter: group g = blockIdx&3 owns rows
// [g*12500,(g+1)*12500); each chunk streams its slice of rr8 and writes only
// its group's rows -> destination region small + group-local, no atomics.
__global__ __launch_bounds__(256) void scatter_rank8_kernel(const uint2* __restrict__ rr8,
                                                            const int* __restrict__ row_ptr,
                                                            unsigned* __restrict__ pk, int E) {
    const int g = blockIdx.x & (SGRP - 1);
    const int chunk = blockIdx.x / SGRP;
    const int CH = (E + SCHUNKS - 1) / SCHUNKS;
    const int lo = chunk * CH;
    const int hi = (lo + CH < E) ? lo + CH : E;
    const int rlo = g * ROWS_PER_SGRP;
    const int rhi = (rlo + ROWS_PER_SGRP < NN) ? rlo + ROWS_PER_SGRP : NN;
    for (int e = lo + threadIdx.x; e < hi; e += 256) {
        uint2 v = rr8[e];
        int r = (int)(v.x >> 16);
        if (r >= rlo && r < rhi) {
            pk[row_ptr[r] + (int)(v.x & 0xffffu)] = v.y;
        }
    }
}

// ---------------- Layer-1 GEMM: out[M,64] = in[M,128] @ W[128,64], bf16 out ----------------
template <int K, bool RELU_IN>
__global__ __launch_bounds__(256) void gemm64_kernel(const float* __restrict__ in,
                                                     const float* __restrict__ Wg,
                                                     unsigned short* __restrict__ outb, int M) {
    constexpr int KC = 64;
    __shared__ float xs[KC][68];
    __shared__ float Ws[KC][64];
    const int t = threadIdx.x;
    const int tx = t % 16;
    const int ty = t / 16;
    const int r0 = blockIdx.x * 64;

    float acc[4][4];
#pragma unroll
    for (int i = 0; i < 4; i++)
#pragma unroll
        for (int j = 0; j < 4; j++) acc[i][j] = 0.f;

    for (int k0 = 0; k0 < K; k0 += KC) {
        for (int i = t * 4; i < KC * 64; i += 1024) {
            *(float4*)&Ws[i / 64][i % 64] = *(const float4*)&Wg[(size_t)k0 * 64 + i];
        }
        {
            const int r = t / 4;
            const int q = t % 4;
            const int gr = r0 + r;
#pragma unroll
            for (int i = 0; i < 4; i++) {
                int k = q * 16 + i * 4;
                float4 v;
                if (gr < M)
                    v = *(const float4*)&in[(size_t)gr * K + k0 + k];
                else
                    v = make_float4(0.f, 0.f, 0.f, 0.f);
                if (RELU_IN) {
                    v.x = fmaxf(v.x, 0.f);
                    v.y = fmaxf(v.y, 0.f);
                    v.z = fmaxf(v.z, 0.f);
                    v.w = fmaxf(v.w, 0.f);
                }
                xs[k + 0][r] = v.x;
                xs[k + 1][r] = v.y;
                xs[k + 2][r] = v.z;
                xs[k + 3][r] = v.w;
            }
        }
        __syncthreads();
#pragma unroll 8
        for (int k = 0; k < KC; k++) {
            float4 xv = *(const float4*)&xs[k][ty * 4];
            float4 wv = *(const float4*)&Ws[k][tx * 4];
            acc[0][0] += xv.x * wv.x; acc[0][1] += xv.x * wv.y;
            acc[0][2] += xv.x * wv.z; acc[0][3] += xv.x * wv.w;
            acc[1][0] += xv.y * wv.x; acc[1][1] += xv.y * wv.y;
            acc[1][2] += xv.y * wv.z; acc[1][3] += xv.y * wv.w;
            acc[2][0] += xv.z * wv.x; acc[2][1] += xv.z * wv.y;
            acc[2][2] += xv.z * wv.z; acc[2][3] += xv.z * wv.w;
            acc[3][0] += xv.w * wv.x; acc[3][1] += xv.w * wv.y;
            acc[3][2] += xv.w * wv.z; acc[3][3] += xv.w * wv.w;
        }
        __syncthreads();
    }
#pragma unroll
    for (int i = 0; i < 4; i++) {
        int r = r0 + ty * 4 + i;
        if (r < M) {
            ushort4 u;
            u.x = f2bf(acc[i][0]);
            u.y = f2bf(acc[i][1]);
            u.z = f2bf(acc[i][2]);
            u.w = f2bf(acc[i][3]);
            *(ushort4*)&outb[(size_t)r * 64 + tx * 4] = u;
        }
    }
}

// ---------------- Fused SpMM(F=64) + next-layer dense GEMM, v3 ----------------
// Quarter-wave mapping: wave = 2 rows x 2 edge-slots x 16 feat-lanes(x4 feats).
// One gather instruction = 2 rows x 2 edges x 2 cache lines = 8 lines in flight;
// an 8-gather batch = 64 lines/wave (2x the ushort2 scheme). Block's contiguous
// edge range staged into 4KB LDS (coalesced, removes divergent pk VMEM loads).
// Epilogue reads W directly from L2 (no Wlt LDS) -> LDS 6KB, VGPR<=64 (8 w/SIMD).
template <int NOUT>
__global__ __launch_bounds__(256, 8) void spmm64_fused_kernel(
    const unsigned short* __restrict__ gb,   // gather source [*,64] bf16
    const int* __restrict__ row_ptr,
    const unsigned* __restrict__ pk,
    const float* __restrict__ bias,
    const float* __restrict__ Wn,            // [64, NOUT] fp32 (next layer)
    float* __restrict__ e_out,               // [M,64] fp32 (required output)
    unsigned short* __restrict__ nxt,        // [M,NOUT] bf16 (next layer input)
    int M) {
    __shared__ float xs[8][64];
    __shared__ unsigned epk[EMAX];
    const int t = threadIdx.x;
    const int lane = t & 63;
    const int rb = t >> 5;            // row-in-block 0..7 (half-wave)
    const int slot = (lane >> 4) & 1; // edge slot within row (quarter-wave)
    const int fl = (lane & 15) * 4;   // feature base: 4 feats per lane

    const int blk0 = blockIdx.x * 8;
    const int base = row_ptr[blk0];
    const int cnt = row_ptr[blk0 + 8] - base;
    const bool fits = (cnt <= EMAX);
    if (fits) {
        for (int i = t; i < cnt; i += 256) epk[i] = pk[base + i];
    }
    __syncthreads();

    const int r = blk0 + rb;
    float a0 = 0.f, a1 = 0.f, a2 = 0.f, a3 = 0.f;

#define FMA_EDGE(q, g)                                              \
    {                                                               \
        float w_ = pk_w(q);                                         \
        a0 += w_ * bf2f((unsigned short)((g).x & 0xffffu));         \
        a1 += w_ * bf2f((unsigned short)((g).x >> 16));             \
        a2 += w_ * bf2f((unsigned short)((g).y & 0xffffu));         \
        a3 += w_ * bf2f((unsigned short)((g).y >> 16));             \
    }
#define GLD(q) (*(const uint2*)&gb[(size_t)pk_c(q) * 64 + fl])

    if (fits) {
        int le = row_ptr[r] - base;
        const int lend = row_ptr[r + 1] - base;
        // 16-edge batches: 8 gathers/lane (2 slots x 8) -> 64 lines/wave in flight
        for (; le + 16 <= lend; le += 16) {
            unsigned q0 = epk[le + 0 + slot], q1 = epk[le + 2 + slot];
            unsigned q2 = epk[le + 4 + slot], q3 = epk[le + 6 + slot];
            unsigned q4 = epk[le + 8 + slot], q5 = epk[le + 10 + slot];
            unsigned q6 = epk[le + 12 + slot], q7 = epk[le + 14 + slot];
            uint2 g0 = GLD(q0), g1 = GLD(q1), g2 = GLD(q2), g3 = GLD(q3);
            uint2 g4 = GLD(q4), g5 = GLD(q5), g6 = GLD(q6), g7 = GLD(q7);
            FMA_EDGE(q0, g0); FMA_EDGE(q1, g1); FMA_EDGE(q2, g2); FMA_EDGE(q3, g3);
            FMA_EDGE(q4, g4); FMA_EDGE(q5, g5); FMA_EDGE(q6, g6); FMA_EDGE(q7, g7);
        }
        // straight-line tail ladder: 8, 4, 2, 1
        if (le + 8 <= lend) {
            unsigned q0 = epk[le + 0 + slot], q1 = epk[le + 2 + slot];
            unsigned q2 = epk[le + 4 + slot], q3 = epk[le + 6 + slot];
            uint2 g0 = GLD(q0), g1 = GLD(q1), g2 = GLD(q2), g3 = GLD(q3);
            FMA_EDGE(q0, g0); FMA_EDGE(q1, g1); FMA_EDGE(q2, g2); FMA_EDGE(q3, g3);
            le += 8;
        }
        if (le + 4 <= lend) {
            unsigned q0 = epk[le + 0 + slot], q1 = epk[le + 2 + slot];
            uint2 g0 = GLD(q0), g1 = GLD(q1);
            FMA_EDGE(q0, g0); FMA_EDGE(q1, g1);
            le += 4;
        }
        if (le + 2 <= lend) {
            unsigned q = epk[le + slot];
            uint2 g = GLD(q);
            FMA_EDGE(q, g);
            le += 2;
        }
        if (le < lend && slot == 0) {  // final odd edge: slot 0 only
            unsigned q = epk[le];
            uint2 g = GLD(q);
            FMA_EDGE(q, g);
        }
    } else {
        // fallback (effectively never taken; correctness only)
        int e = row_ptr[r];
        const int end = row_ptr[r + 1];
        for (; e + 2 <= end; e += 2) {
            unsigned q = pk[e + slot];
            uint2 g = GLD(q);
            FMA_EDGE(q, g);
        }
        if (e < end && slot == 0) {
            unsigned q = pk[e];
            uint2 g = GLD(q);
            FMA_EDGE(q, g);
        }
    }
#undef FMA_EDGE
#undef GLD

    // combine the two edge slots (lane x and x^16 hold same feats of same row)
    a0 += __shfl_xor(a0, 16);
    a1 += __shfl_xor(a1, 16);
    a2 += __shfl_xor(a2, 16);
    a3 += __shfl_xor(a3, 16);

    if (slot == 0) {
        float4 b4 = *(const float4*)&bias[fl];
        float4 v;
        v.x = a0 + b4.x;
        v.y = a1 + b4.y;
        v.z = a2 + b4.z;
        v.w = a3 + b4.w;
        *(float4*)&e_out[(size_t)r * 64 + fl] = v;
        xs[rb][fl + 0] = fmaxf(v.x, 0.f);
        xs[rb][fl + 1] = fmaxf(v.y, 0.f);
        xs[rb][fl + 2] = fmaxf(v.z, 0.f);
        xs[rb][fl + 3] = fmaxf(v.w, 0.f);
    }
    __syncthreads();

    // Epilogue GEMM: nxt[r][j] = sum_k relu(e[r][k]) * W[k][j]; W from L2 (coalesced per k)
    if (NOUT == 64) {
        const int rblk = t >> 6;  // wave-uniform -> xs reads broadcast (free)
        const int j = t & 63;
        float acc0 = 0.f, acc1 = 0.f;
#pragma unroll 16
        for (int k = 0; k < 64; k++) {
            float w = Wn[k * 64 + j];
            acc0 += xs[rblk][k] * w;
            acc1 += xs[rblk + 4][k] * w;
        }
        nxt[(size_t)(blk0 + rblk) * 64 + j] = f2bf(acc0);
        nxt[(size_t)(blk0 + rblk + 4) * 64 + j] = f2bf(acc1);
    } else {
        if (t < 8 * NOUT) {
            const int rr = t / NOUT;
            const int j = t % NOUT;
            float acc = 0.f;
#pragma unroll 16
            for (int k = 0; k < 64; k++) acc += xs[rr][k] * Wn[k * NOUT + j];
            nxt[(size_t)(blk0 + rr) * NOUT + j] = f2bf(acc);
        }
    }
}

// ---------------- SpMM (F=16) fused with log_softmax ----------------
// One row per wave64: lane = 16*slot + f, 4 edge slots in parallel, shfl-reduce.
__global__ __launch_bounds__(256) void spmm16_lsm_kernel(const unsigned short* __restrict__ tmpc,
                                                         const int* __restrict__ row_ptr,
                                                         const unsigned* __restrict__ pk,
                                                         const float* __restrict__ bias,
                                                         float* __restrict__ e5,
                                                         float* __restrict__ out0, int M) {
    const int t = threadIdx.x;
    const int wv = __builtin_amdgcn_readfirstlane(t >> 6);  // wave 0..3
    const int lane = t & 63;
    const int f = lane & 15;
    const int s = lane >> 4;  // slot 0..3
    const int r = blockIdx.x * 4 + wv;
    if (r >= M) return;

    int e = row_ptr[r];
    const int end = row_ptr[r + 1];
    float acc = 0.f;
    for (; e + 8 <= end; e += 8) {
        unsigned qa = pk[e + s];
        unsigned qb = pk[e + 4 + s];
        acc += pk_w(qa) * bf2f(tmpc[(size_t)pk_c(qa) * 16 + f]);
        acc += pk_w(qb) * bf2f(tmpc[(size_t)pk_c(qb) * 16 + f]);
    }
    if (e + 4 <= end) {
        unsigned q = pk[e + s];
        acc += pk_w(q) * bf2f(tmpc[(size_t)pk_c(q) * 16 + f]);
        e += 4;
    }
    if (s < end - e) {
        unsigned q = pk[e + s];
        acc += pk_w(q) * bf2f(tmpc[(size_t)pk_c(q) * 16 + f]);
    }
    acc += __shfl_xor(acc, 16);
    acc += __shfl_xor(acc, 32);
    float v = acc + bias[f];

    float m = v;
#pragma unroll
    for (int off = 1; off < 16; off <<= 1) m = fmaxf(m, __shfl_xor(m, off, 16));
    float sum = expf(v - m);
#pragma unroll
    for (int off = 1; off < 16; off <<= 1) sum += __shfl_xor(sum, off, 16);
    float ls = logf(sum);
    if (lane < 16) {
        e5[(size_t)r * 16 + f] = v;
        out0[(size_t)r * 16 + f] = v - m - ls;
    }
}

// ---------------- launch ----------------

extern "C" void kernel_launch(void* const* d_in, const int* in_sizes, int n_in,
                              void* d_out, int out_size, void* d_ws, size_t ws_size,
                              hipStream_t stream) {
    const float* x = (const float*)d_in[0];
    const int* erow = (const int*)d_in[1];
    const int* ecol = (const int*)d_in[2];
    const float* ew = (const float*)d_in[3];
    const float* W1 = (const float*)d_in[4];
    const float* b1 = (const float*)d_in[5];
    const float* W2 = (const float*)d_in[6];
    const float* b2 = (const float*)d_in[7];
    const float* W3 = (const float*)d_in[8];
    const float* b3 = (const float*)d_in[9];
    const float* W4 = (const float*)d_in[10];
    const float* b4 = (const float*)d_in[11];
    const float* W5 = (const float*)d_in[12];
    const float* b5 = (const float*)d_in[13];

    // Output layout: log_softmax(e5), e1, e2, e3, e4, e5
    float* out0 = (float*)d_out;
    float* e1 = out0 + (size_t)NN * NCLASS;
    float* e2 = e1 + (size_t)NN * NHID;
    float* e3 = e2 + (size_t)NN * NHID;
    float* e4 = e3 + (size_t)NN * NHID;
    float* e5 = e4 + (size_t)NN * NHID;

    // Workspace layout
    char* ws = (char*)d_ws;
    unsigned short* tmpA = (unsigned short*)ws; ws += (size_t)NN * NHID * 2;   // 6.4 MB
    unsigned short* tmpB = (unsigned short*)ws; ws += (size_t)NN * NHID * 2;   // 6.4 MB
    unsigned short* tmpc = (unsigned short*)ws; ws += ((size_t)NN * NCLASS * 2 + 255) / 256 * 256;  // 1.6 MB
    int* deg = (int*)ws;      ws += ((size_t)NN * 4 + 255) / 256 * 256;        // zeroed below
    int* row_ptr = (int*)ws;  ws += ((size_t)(NN + 1) * 4 + 255) / 256 * 256;
    int* blocksum = (int*)ws; ws += ((size_t)NB_SCAN * 4 + 255) / 256 * 256;
    uint2* rr8 = (uint2*)ws;  ws += (size_t)NE * 8;                            // 6.4 MB packed records
    unsigned* pk = (unsigned*)ws; ws += (size_t)NE * 4;                        // 3.2 MB packed edges

    // ---- CSR build: pack+rank, scans, static partitioned rank-scatter ----
    hipMemsetAsync(deg, 0, (size_t)NN * 4, stream);
    hist_pack_kernel<<<(NE + 255) / 256, 256, 0, stream>>>(erow, ecol, ew, deg, rr8, NE);
    scan_sum_kernel<<<NB_SCAN, 256, 0, stream>>>(deg, blocksum, NN);
    scan_final_kernel<<<NB_SCAN, 256, 0, stream>>>(deg, blocksum, row_ptr, NN);
    scatter_rank8_kernel<<<SGRP * SCHUNKS, 256, 0, stream>>>(rr8, row_ptr, pk, NE);

    // ---- Layer 1 dense: tmpA = x @ W1 (bf16) ----
    gemm64_kernel<NFEAT, false><<<GB, 256, 0, stream>>>(x, W1, tmpA, NN);

    // ---- Layers 1-4: fused SpMM + next dense GEMM ----
    const int FG = NN / 8;  // 6250 blocks x 8 rows
    spmm64_fused_kernel<64><<<FG, 256, 0, stream>>>(tmpA, row_ptr, pk, b1, W2, e1, tmpB, NN);
    spmm64_fused_kernel<64><<<FG, 256, 0, stream>>>(tmpB, row_ptr, pk, b2, W3, e2, tmpA, NN);
    spmm64_fused_kernel<64><<<FG, 256, 0, stream>>>(tmpA, row_ptr, pk, b3, W4, e3, tmpB, NN);
    spmm64_fused_kernel<16><<<FG, 256, 0, stream>>>(tmpB, row_ptr, pk, b4, W5, e4, tmpc, NN);

    // ---- Layer 5: SpMM(F=16) fused with log_softmax ----
    spmm16_lsm_kernel<<<(NN + 3) / 4, 256, 0, stream>>>(tmpc, row_ptr, pk, b5, e5, out0, NN);
}